// Round 1
// baseline (375.398 us; speedup 1.0000x reference)
//
#include <hip/hip_runtime.h>

// GNNEncoder fused kernel, fp32 vector-ALU version (round 1 baseline).
// B=16, S=2048, N=64, HD=32. out[b, i*HD+f'] = mean_s relu(fc2([h|agg])).
#define BB 16
#define SS 2048
#define NN 64
#define HDD 32
#define S_CHUNK 32
#define BLOCKS_PER_B (SS / S_CHUNK) // 64

__global__ __launch_bounds__(256, 2) void gnn_fused(
    const float* __restrict__ x,    // [B,S,N]
    const float* __restrict__ adj,  // [N,N]
    const float* __restrict__ w1,   // [HD]
    const float* __restrict__ b1,   // [HD]
    const float* __restrict__ w2,   // [HD, 2*HD]
    const float* __restrict__ b2,   // [HD]
    float* __restrict__ out)        // [B, N*HD]
{
    __shared__ float At[NN][NN];    // At[j][i] = adj_norm[i][j] (transposed)
    __shared__ float hs[NN][HDD];   // h[j][f]
    __shared__ float aggs[NN][HDD]; // agg[i][f]
    __shared__ float xs[NN];
    __shared__ float rs[NN];

    const int tid = threadIdx.x;
    const int b   = blockIdx.x / BLOCKS_PER_B;
    const int sc  = blockIdx.x % BLOCKS_PER_B;
    const int s0  = sc * S_CHUNK;

    const int f  = tid & (HDD - 1); // 0..31
    const int ig = tid >> 5;        // 0..7, handles i/j = ig*8 .. ig*8+7

    // --- row-normalized adjacency, transposed, into LDS ---
    if (tid < NN) {
        float sum = 0.f;
        #pragma unroll 8
        for (int j = 0; j < NN; ++j) sum += adj[tid * NN + j];
        rs[tid] = 1.0f / (sum + 1e-8f);
    }
    __syncthreads();
    for (int e = tid; e < NN * NN; e += 256) {
        int i = e >> 6, j = e & 63;
        At[j][i] = adj[i * NN + j] * rs[i];
    }

    // --- per-thread constants (f' = f for fc2 phase) ---
    const float w1f = w1[f];
    const float b1f = b1[f];
    const float b2f = b2[f];
    float w2r[2 * HDD];
    #pragma unroll
    for (int k = 0; k < 2 * HDD; ++k) w2r[k] = w2[f * (2 * HDD) + k];

    float macc[8];
    #pragma unroll
    for (int r = 0; r < 8; ++r) macc[r] = 0.f;

    __syncthreads();

    for (int ss = 0; ss < S_CHUNK; ++ss) {
        const int s = s0 + ss;
        if (tid < NN) xs[tid] = x[((size_t)b * SS + s) * NN + tid];
        __syncthreads();

        // h[j][f] = relu(x[j]*w1[f] + b1[f]); thread covers 8 j's, fixed f
        #pragma unroll
        for (int r = 0; r < 8; ++r) {
            const int j = ig * 8 + r;
            hs[j][f] = fmaxf(xs[j] * w1f + b1f, 0.f);
        }
        __syncthreads();

        // agg[i][f] = sum_j At[j][i]*h[j][f]; thread covers 8 i's, fixed f
        float acc[8];
        #pragma unroll
        for (int r = 0; r < 8; ++r) acc[r] = 0.f;
        #pragma unroll 8
        for (int j = 0; j < NN; ++j) {
            const float hj = hs[j][f];                      // broadcast read
            const float4* arow = (const float4*)&At[j][ig * 8];
            const float4 a0 = arow[0], a1 = arow[1];
            acc[0] += a0.x * hj; acc[1] += a0.y * hj;
            acc[2] += a0.z * hj; acc[3] += a0.w * hj;
            acc[4] += a1.x * hj; acc[5] += a1.y * hj;
            acc[6] += a1.z * hj; acc[7] += a1.w * hj;
        }
        #pragma unroll
        for (int r = 0; r < 8; ++r) aggs[ig * 8 + r][f] = acc[r];
        __syncthreads();

        // h2[i][f'] = relu(h[i][:]·W2a[f'] + agg[i][:]·W2b[f'] + b2[f'])
        #pragma unroll
        for (int r = 0; r < 8; ++r) {
            const int i = ig * 8 + r;
            float v = b2f;
            const float4* hrow = (const float4*)&hs[i][0];   // broadcast reads
            const float4* grow = (const float4*)&aggs[i][0];
            #pragma unroll
            for (int q = 0; q < HDD / 4; ++q) {
                const float4 hv = hrow[q];
                v += hv.x * w2r[q * 4 + 0] + hv.y * w2r[q * 4 + 1]
                   + hv.z * w2r[q * 4 + 2] + hv.w * w2r[q * 4 + 3];
            }
            #pragma unroll
            for (int q = 0; q < HDD / 4; ++q) {
                const float4 gv = grow[q];
                v += gv.x * w2r[HDD + q * 4 + 0] + gv.y * w2r[HDD + q * 4 + 1]
                   + gv.z * w2r[HDD + q * 4 + 2] + gv.w * w2r[HDD + q * 4 + 3];
            }
            macc[r] += fmaxf(v, 0.f);
        }
        __syncthreads(); // protect hs/aggs/xs before next iteration overwrites
    }

    const float inv = 1.0f / (float)SS;
    #pragma unroll
    for (int r = 0; r < 8; ++r) {
        const int i = ig * 8 + r;
        atomicAdd(&out[(size_t)b * (NN * HDD) + i * HDD + f], macc[r] * inv);
    }
}

extern "C" void kernel_launch(void* const* d_in, const int* in_sizes, int n_in,
                              void* d_out, int out_size, void* d_ws, size_t ws_size,
                              hipStream_t stream) {
    const float* x    = (const float*)d_in[0];
    const float* adj  = (const float*)d_in[1];
    const float* w1   = (const float*)d_in[2];
    const float* b1   = (const float*)d_in[3];
    const float* w2   = (const float*)d_in[4];
    const float* b2   = (const float*)d_in[5];
    float* out = (float*)d_out;

    hipMemsetAsync(out, 0, (size_t)out_size * sizeof(float), stream);
    dim3 grid(BB * BLOCKS_PER_B);
    dim3 block(256);
    gnn_fused<<<grid, block, 0, stream>>>(x, adj, w1, b1, w2, b2, out);
}

// Round 2
// 115.365 us; speedup vs baseline: 3.2540x; 3.2540x over previous
//
#include <hip/hip_runtime.h>

// GNNEncoder fused MFMA kernel (round 2).
// B=16, S=2048, N=64, HD=32.
// GEMM1: aggT[(s,f), i] = sum_j h[(s,f), j] * An[i][j]   (A=h in regs, B=An in regs)
// GEMM2: h2[(s,i), f']  = sum_k cat[(s,i), k] * W2T[k,f'] (A: h-part in regs, agg from LDS)
#define BN 16
#define SN 2048
#define NV 64
#define HD 32
#define TCH 8               // s per sub-chunk
#define SCHUNK 64           // s per block
#define NSUB (SCHUNK / TCH) // 8
#define CATP 40             // padded f-dim of agg LDS (80 B rows, 16B-aligned)

typedef short  bf8_t  __attribute__((ext_vector_type(8)));   // raw-bit view for builtin
typedef __bf16 bfv8   __attribute__((ext_vector_type(8)));
typedef __bf16 bfv4   __attribute__((ext_vector_type(4)));
typedef float  f32x16 __attribute__((ext_vector_type(16)));

#define MFMA32(a, b, c) __builtin_amdgcn_mfma_f32_32x32x16_bf16( \
    __builtin_bit_cast(bf8_t, (a)), __builtin_bit_cast(bf8_t, (b)), (c), 0, 0, 0)

__global__ __launch_bounds__(256, 2) void gnn_mfma(
    const float* __restrict__ x,    // [B,S,N]
    const float* __restrict__ adj,  // [N,N]
    const float* __restrict__ w1,   // [HD]
    const float* __restrict__ b1,   // [HD]
    const float* __restrict__ w2,   // [HD, 2*HD]
    const float* __restrict__ b2,   // [HD]
    float* __restrict__ out)        // [B, N*HD]
{
    __shared__ float  xs[TCH][NV];          // 2 KB
    __shared__ __bf16 catg[TCH][NV][CATP];  // 40 KB, wave-private slices by s
    __shared__ float  red[NV * HD];         // 8 KB
    __shared__ float  rs[NV];

    const int tid  = threadIdx.x;
    const int w    = tid >> 6;
    const int lane = tid & 63;
    const int l31  = lane & 31;
    const int lh   = lane >> 5;             // 0/1 half-wave
    const int b    = blockIdx.x >> 5;
    const int chk  = blockIdx.x & 31;
    const int sbase = chk * SCHUNK;

    // zero the block reduce buffer
    #pragma unroll
    for (int q = 0; q < (NV * HD) / 256; ++q) red[tid + q * 256] = 0.f;

    // adjacency row inverse sums
    if (tid < NV) {
        float s = 0.f;
        const float4* r4 = (const float4*)(adj + tid * NV);
        #pragma unroll
        for (int q = 0; q < NV / 4; ++q) { float4 v = r4[q]; s += v.x + v.y + v.z + v.w; }
        rs[tid] = 1.f / (s + 1e-8f);
    }
    __syncthreads();

    // --- An B-fragments (GEMM1), held in registers for the whole block ---
    // B[k=j][n=i]: lane -> n = nt*32+l31, k = kk*16 + lh*8 + e  => An[i][j] row-major
    bfv8 an[2][4];
    #pragma unroll
    for (int nt = 0; nt < 2; ++nt) {
        const int i = nt * 32 + l31;
        const float rsi = rs[i];
        #pragma unroll
        for (int kk = 0; kk < 4; ++kk) {
            const int j0 = kk * 16 + lh * 8;
            const float4 a0 = *(const float4*)(adj + i * NV + j0);
            const float4 a1 = *(const float4*)(adj + i * NV + j0 + 4);
            bfv8 v;
            v[0] = (__bf16)(a0.x * rsi); v[1] = (__bf16)(a0.y * rsi);
            v[2] = (__bf16)(a0.z * rsi); v[3] = (__bf16)(a0.w * rsi);
            v[4] = (__bf16)(a1.x * rsi); v[5] = (__bf16)(a1.y * rsi);
            v[6] = (__bf16)(a1.z * rsi); v[7] = (__bf16)(a1.w * rsi);
            an[nt][kk] = v;
        }
    }

    // --- W2^T B-fragments (GEMM2) ---
    // B[k][n=f']: lane -> f' = l31, k = kk*16 + lh*8 + e => w2[f'][k]
    bfv8 wf[4];
    #pragma unroll
    for (int kk = 0; kk < 4; ++kk) {
        const int k0 = kk * 16 + lh * 8;
        const float4 a0 = *(const float4*)(w2 + l31 * (2 * HD) + k0);
        const float4 a1 = *(const float4*)(w2 + l31 * (2 * HD) + k0 + 4);
        bfv8 v;
        v[0] = (__bf16)a0.x; v[1] = (__bf16)a0.y; v[2] = (__bf16)a0.z; v[3] = (__bf16)a0.w;
        v[4] = (__bf16)a1.x; v[5] = (__bf16)a1.y; v[6] = (__bf16)a1.z; v[7] = (__bf16)a1.w;
        wf[kk] = v;
    }

    // per-lane fc1/fc2 constants
    const float w1f = w1[l31];
    const float b1f = b1[l31];
    const float b2f = b2[l31];
    float w1k[2][8], b1k[2][8];
    #pragma unroll
    for (int kk = 0; kk < 2; ++kk) {
        const int k0 = kk * 16 + lh * 8;
        #pragma unroll
        for (int e = 0; e < 8; ++e) { w1k[kk][e] = w1[k0 + e]; b1k[kk][e] = b1[k0 + e]; }
    }

    f32x16 macc0, macc1;   // mean accumulators, ihalf = 0 / 1
    #pragma unroll
    for (int r = 0; r < 16; ++r) { macc0[r] = 0.f; macc1[r] = 0.f; }

    for (int t = 0; t < NSUB; ++t) {
        __syncthreads();   // protect xs from previous iteration's readers
        if (tid < 128) {
            ((float4*)&xs[0][0])[tid] =
                ((const float4*)(x + ((size_t)b * SN + sbase + t * TCH) * (size_t)NV))[tid];
        }
        __syncthreads();

        // ---- Phase 1: GEMM1 -> aggT, written to catg (wave-private s slices) ----
        #pragma unroll
        for (int sp = 0; sp < 2; ++sp) {
            const int sl = 2 * w + sp;
            bfv8 a1f[4];
            #pragma unroll
            for (int kk = 0; kk < 4; ++kk) {
                const int j0 = kk * 16 + lh * 8;
                const float4 xa = *(const float4*)&xs[sl][j0];
                const float4 xb = *(const float4*)&xs[sl][j0 + 4];
                bfv8 v;
                v[0] = (__bf16)fmaxf(xa.x * w1f + b1f, 0.f);
                v[1] = (__bf16)fmaxf(xa.y * w1f + b1f, 0.f);
                v[2] = (__bf16)fmaxf(xa.z * w1f + b1f, 0.f);
                v[3] = (__bf16)fmaxf(xa.w * w1f + b1f, 0.f);
                v[4] = (__bf16)fmaxf(xb.x * w1f + b1f, 0.f);
                v[5] = (__bf16)fmaxf(xb.y * w1f + b1f, 0.f);
                v[6] = (__bf16)fmaxf(xb.z * w1f + b1f, 0.f);
                v[7] = (__bf16)fmaxf(xb.w * w1f + b1f, 0.f);
                a1f[kk] = v;
            }
            #pragma unroll
            for (int nt = 0; nt < 2; ++nt) {
                f32x16 c;
                #pragma unroll
                for (int r = 0; r < 16; ++r) c[r] = 0.f;
                #pragma unroll
                for (int kk = 0; kk < 4; ++kk) c = MFMA32(a1f[kk], an[nt][kk], c);
                // C[m=(sl,f)][n=i]: col=l31 -> i, row=(reg&3)+8*(reg>>2)+4*lh -> f
                const int i = nt * 32 + l31;
                #pragma unroll
                for (int g = 0; g < 4; ++g) {
                    const int f0 = g * 8 + 4 * lh;
                    bfv4 pv;
                    pv[0] = (__bf16)c[g * 4 + 0]; pv[1] = (__bf16)c[g * 4 + 1];
                    pv[2] = (__bf16)c[g * 4 + 2]; pv[3] = (__bf16)c[g * 4 + 3];
                    *(bfv4*)&catg[sl][i][f0] = pv;
                }
            }
        }

        // ---- Phase 2: GEMM2 (same-wave catg slices; compiler orders ds ops) ----
        #pragma unroll
        for (int p = 0; p < 4; ++p) {
            const int mt = 4 * w + p;
            const int sl = mt >> 1;          // in {2w, 2w+1}
            const int ih = mt & 1;
            const int i  = ih * 32 + l31;
            const float xv = xs[sl][i];
            f32x16 c;
            #pragma unroll
            for (int r = 0; r < 16; ++r) c[r] = 0.f;
            #pragma unroll
            for (int kk = 0; kk < 2; ++kk) {   // h part, k in [0,32)
                bfv8 v;
                #pragma unroll
                for (int e = 0; e < 8; ++e)
                    v[e] = (__bf16)fmaxf(xv * w1k[kk][e] + b1k[kk][e], 0.f);
                c = MFMA32(v, wf[kk], c);
            }
            #pragma unroll
            for (int kk = 2; kk < 4; ++kk) {   // agg part, k in [32,64)
                bfv8 v = *(const bfv8*)&catg[sl][i][(kk - 2) * 16 + lh * 8];
                c = MFMA32(v, wf[kk], c);
            }
            #pragma unroll
            for (int r = 0; r < 16; ++r) {
                const float h2 = fmaxf(c[r] + b2f, 0.f);
                if (ih == 0) macc0[r] += h2; else macc1[r] += h2;
            }
        }
    }

    // ---- epilogue: cross-wave reduce in LDS, then global atomics ----
    #pragma unroll
    for (int r = 0; r < 16; ++r) {
        const int row = (r & 3) + 8 * (r >> 2) + 4 * lh;  // i within half
        atomicAdd(&red[row * HD + l31], macc0[r]);
        atomicAdd(&red[(row + 32) * HD + l31], macc1[r]);
    }
    __syncthreads();
    const float inv = 1.f / (float)SN;
    #pragma unroll
    for (int q = 0; q < (NV * HD) / 256; ++q) {
        const int e = tid + q * 256;
        atomicAdd(out + (size_t)b * (NV * HD) + e, red[e] * inv);
    }
}

extern "C" void kernel_launch(void* const* d_in, const int* in_sizes, int n_in,
                              void* d_out, int out_size, void* d_ws, size_t ws_size,
                              hipStream_t stream) {
    const float* x   = (const float*)d_in[0];
    const float* adj = (const float*)d_in[1];
    const float* w1  = (const float*)d_in[2];
    const float* b1  = (const float*)d_in[3];
    const float* w2  = (const float*)d_in[4];
    const float* b2  = (const float*)d_in[5];
    float* out = (float*)d_out;

    hipMemsetAsync(out, 0, (size_t)out_size * sizeof(float), stream);
    gnn_mfma<<<dim3(BN * 32), dim3(256), 0, stream>>>(x, adj, w1, b1, w2, b2, out);
}